// Round 1
// baseline (59.644 us; speedup 1.0000x reference)
//
#include <hip/hip_runtime.h>
#include <hip/hip_bf16.h>

// Problem constants (fixed by the reference):
// B=16, S=40, P=512, L=48, SEQ=2048, H=1024
#define CB   16
#define CS   40
#define CP   512
#define CL   48
#define CSEQ 2048
#define CH   1024
#define H4   (CH / 4)   // 256 float4 per row

// ---------------------------------------------------------------------------
// Kernel 1: per-batch sentence bookkeeping.
// tok[b,s]    = (s < passage_length[b]) ? sentence_length[b,s]-1 : 0
// starts[b,s] = 1 + exclusive_cumsum_s(tok)
// One block, CB threads; each thread walks its batch's 40 sentences serially.
// ---------------------------------------------------------------------------
__global__ void setup_kernel(const int* __restrict__ sentence_length,
                             const int* __restrict__ passage_length,
                             int* __restrict__ tok_out,
                             int* __restrict__ starts_out) {
    int b = threadIdx.x;
    if (b >= CB) return;
    int pl  = passage_length[b];
    int acc = 0;
    for (int s = 0; s < CS; ++s) {
        int t = (s < pl) ? (sentence_length[b * CS + s] - 1) : 0;
        tok_out[b * CS + s]    = t;
        starts_out[b * CS + s] = 1 + acc;
        acc += t;
    }
}

// ---------------------------------------------------------------------------
// Kernel 2: sen_emb gather + per-sentence sum.
// Block = one (b,s); 256 threads, each owns one float4 column slice of H.
// Loop t=0..L-1: load top_rep row (or zero), store sen_emb, accumulate.
// ---------------------------------------------------------------------------
__global__ void __launch_bounds__(256)
sen_emb_kernel(const float* __restrict__ top_rep,
               const int* __restrict__ tok_arr,
               const int* __restrict__ starts_arr,
               float* __restrict__ sen_emb,
               float* __restrict__ sent_sum) {
    const int blk = blockIdx.x;        // b*S + s
    const int b   = blk / CS;
    const int h4  = threadIdx.x;       // 0..255

    const int tok   = tok_arr[blk];
    const int start = starts_arr[blk];

    const float4* __restrict__ rep =
        reinterpret_cast<const float4*>(top_rep) + (size_t)b * CSEQ * H4;
    float4* __restrict__ out =
        reinterpret_cast<float4*>(sen_emb) + (size_t)blk * CL * H4;

    float4 acc = make_float4(0.f, 0.f, 0.f, 0.f);

    #pragma unroll 4
    for (int t = 0; t < CL; ++t) {
        float4 v = make_float4(0.f, 0.f, 0.f, 0.f);
        if (t < tok) {
            int row = start + t;
            row = min(max(row, 0), CSEQ - 1);
            v = rep[(size_t)row * H4 + h4];
        }
        out[(size_t)t * H4 + h4] = v;
        acc.x += v.x; acc.y += v.y; acc.z += v.z; acc.w += v.w;
    }

    reinterpret_cast<float4*>(sent_sum)[(size_t)blk * H4 + h4] = acc;
}

// ---------------------------------------------------------------------------
// Kernel 3: cls = masked (sent_sum[p0] + sent_sum[p1]) / max(c0+c1, 1)
// Block = one (b,i); 256 threads, float4 each.
// ---------------------------------------------------------------------------
__global__ void __launch_bounds__(256)
cls_kernel(const int* __restrict__ pairs_list,
           const int* __restrict__ pairs_num,
           const int* __restrict__ tok_arr,
           const float* __restrict__ sent_sum,
           float* __restrict__ cls) {
    const int blk = blockIdx.x;        // b*P + i
    const int b   = blk / CP;
    const int i   = blk - b * CP;
    const int h4  = threadIdx.x;

    float4 r = make_float4(0.f, 0.f, 0.f, 0.f);

    if (i < pairs_num[b]) {
        int p0 = pairs_list[(size_t)blk * 2 + 0];
        int p1 = pairs_list[(size_t)blk * 2 + 1];
        p0 = min(max(p0, 0), CS - 1);
        p1 = min(max(p1, 0), CS - 1);

        const float c0 = (float)tok_arr[b * CS + p0];
        const float c1 = (float)tok_arr[b * CS + p1];
        const float denom = fmaxf(c0 + c1, 1.0f);

        const float4* __restrict__ ss = reinterpret_cast<const float4*>(sent_sum);
        float4 a0 = ss[(size_t)(b * CS + p0) * H4 + h4];
        float4 a1 = ss[(size_t)(b * CS + p1) * H4 + h4];

        r.x = (a0.x + a1.x) / denom;
        r.y = (a0.y + a1.y) / denom;
        r.z = (a0.z + a1.z) / denom;
        r.w = (a0.w + a1.w) / denom;
    }

    reinterpret_cast<float4*>(cls)[(size_t)blk * H4 + h4] = r;
}

// ---------------------------------------------------------------------------
// Launch
// ---------------------------------------------------------------------------
extern "C" void kernel_launch(void* const* d_in, const int* in_sizes, int n_in,
                              void* d_out, int out_size, void* d_ws, size_t ws_size,
                              hipStream_t stream) {
    const int*   sentence_length = (const int*)  d_in[0];   // (B,S)
    const int*   pairs_list      = (const int*)  d_in[1];   // (B,P,2)
    const int*   passage_length  = (const int*)  d_in[2];   // (B,)
    const int*   pairs_num       = (const int*)  d_in[3];   // (B,)
    // d_in[4] = max_sentence_length scalar (compile-time CL here)
    const float* top_rep         = (const float*)d_in[5];   // (B,SEQ,H)

    float* out     = (float*)d_out;
    float* sen_emb = out;                                   // (B,S,L,H)
    float* cls     = out + (size_t)CB * CS * CL * CH;       // (B,P,1,H)

    // Workspace layout: sent_sum (B*S*H f32) | tok (B*S i32) | starts (B*S i32)
    float* sent_sum = (float*)d_ws;
    int*   tok_ws   = (int*)((char*)d_ws + (size_t)CB * CS * CH * sizeof(float));
    int*   start_ws = tok_ws + CB * CS;

    setup_kernel<<<1, 64, 0, stream>>>(sentence_length, passage_length,
                                       tok_ws, start_ws);

    sen_emb_kernel<<<CB * CS, 256, 0, stream>>>(top_rep, tok_ws, start_ws,
                                                sen_emb, sent_sum);

    cls_kernel<<<CB * CP, 256, 0, stream>>>(pairs_list, pairs_num, tok_ws,
                                            sent_sum, cls);
}

// Round 2
// 45.531 us; speedup vs baseline: 1.3100x; 1.3100x over previous
//
#include <hip/hip_runtime.h>
#include <hip/hip_bf16.h>

// Problem constants (fixed by the reference):
// B=16, S=40, P=512, L=48, SEQ=2048, H=1024
#define CB   16
#define CS   40
#define CP   512
#define CL   48
#define CSEQ 2048
#define CH   1024
#define H4     (CH / 4)  // 256 float4 per row
#define TCHUNK 8         // t-rows per block
#define NCHUNK (CL / TCHUNK)  // 6 chunks per (b,s)

typedef float fvec4 __attribute__((ext_vector_type(4)));

// ---------------------------------------------------------------------------
// Kernel A: fused bookkeeping + sen_emb gather + partial sums.
// Block = one (b, s, chunk); 256 threads, each owns one float4 column slice.
// starts[b,s] computed in-wave via prefix scan of sentence_length (no setup
// kernel, no inter-kernel dependency). Each block handles TCHUNK t-rows and
// writes a partial column-sum to ws.
// ---------------------------------------------------------------------------
__global__ void __launch_bounds__(256)
gather_kernel(const float* __restrict__ top_rep,
              const int* __restrict__ sentence_length,
              const int* __restrict__ passage_length,
              float* __restrict__ sen_emb,
              float* __restrict__ partial) {
    const int blk   = blockIdx.x;            // (b*CS + s)*NCHUNK + chunk
    const int chunk = blk % NCHUNK;
    const int bs    = blk / NCHUNK;
    const int b     = bs / CS;
    const int s     = bs - b * CS;
    const int h4    = threadIdx.x;           // 0..255
    const int lane  = threadIdx.x & 63;

    // Redundant per-wave prefix scan over the 40 sentences of batch b.
    // tok[s'] = (s' < pl) ? sl[b,s']-1 : 0 ;  start[s] = 1 + excl_cumsum(tok)
    const int pl = passage_length[b];
    int tokl = 0;
    if (lane < CS && lane < pl) tokl = sentence_length[b * CS + lane] - 1;
    int x = tokl;
    #pragma unroll
    for (int off = 1; off < 64; off <<= 1) {
        int y = __shfl_up(x, off);
        if (lane >= off) x += y;
    }
    const int tok   = __shfl(tokl, s);
    const int start = 1 + __shfl(x, s) - tok;   // exclusive cumsum + 1

    const fvec4* __restrict__ rep =
        reinterpret_cast<const fvec4*>(top_rep) + (size_t)b * CSEQ * H4;
    fvec4* __restrict__ out =
        reinterpret_cast<fvec4*>(sen_emb) +
        ((size_t)bs * CL + (size_t)chunk * TCHUNK) * H4;

    fvec4 acc = {0.f, 0.f, 0.f, 0.f};
    const int t0 = chunk * TCHUNK;

    #pragma unroll
    for (int i = 0; i < TCHUNK; ++i) {
        const int t = t0 + i;
        fvec4 v = {0.f, 0.f, 0.f, 0.f};
        if (t < tok) {
            // valid rows satisfy 1 <= start+t <= 1881 < SEQ; clamp for safety
            int row = start + t;
            row = min(max(row, 0), CSEQ - 1);
            v = rep[(size_t)row * H4 + h4];
        }
        __builtin_nontemporal_store(v, &out[(size_t)i * H4 + h4]);
        acc += v;
    }

    // cached store: reduce kernel re-reads these from L2/L3
    reinterpret_cast<fvec4*>(partial)[(size_t)blk * H4 + h4] = acc;
}

// ---------------------------------------------------------------------------
// Kernel B: sent_sum[bs] = sum over NCHUNK partials.
// ---------------------------------------------------------------------------
__global__ void __launch_bounds__(256)
reduce_kernel(const float* __restrict__ partial,
              float* __restrict__ sent_sum) {
    const int bs = blockIdx.x;
    const int h4 = threadIdx.x;
    const fvec4* __restrict__ p =
        reinterpret_cast<const fvec4*>(partial) + (size_t)bs * NCHUNK * H4;
    fvec4 acc = p[h4];
    #pragma unroll
    for (int c = 1; c < NCHUNK; ++c) acc += p[(size_t)c * H4 + h4];
    reinterpret_cast<fvec4*>(sent_sum)[(size_t)bs * H4 + h4] = acc;
}

// ---------------------------------------------------------------------------
// Kernel C: cls = masked (sent_sum[p0] + sent_sum[p1]) / max(c0+c1, 1)
// Counts derived directly from sentence_length/passage_length (no tok array).
// ---------------------------------------------------------------------------
__global__ void __launch_bounds__(256)
cls_kernel(const int* __restrict__ pairs_list,
           const int* __restrict__ pairs_num,
           const int* __restrict__ sentence_length,
           const int* __restrict__ passage_length,
           const float* __restrict__ sent_sum,
           float* __restrict__ cls) {
    const int blk = blockIdx.x;              // b*CP + i
    const int b   = blk / CP;
    const int i   = blk - b * CP;
    const int h4  = threadIdx.x;

    fvec4 r = {0.f, 0.f, 0.f, 0.f};

    if (i < pairs_num[b]) {
        int p0 = pairs_list[(size_t)blk * 2 + 0];
        int p1 = pairs_list[(size_t)blk * 2 + 1];
        p0 = min(max(p0, 0), CS - 1);
        p1 = min(max(p1, 0), CS - 1);

        const int pl = passage_length[b];
        const float c0 = (p0 < pl) ? (float)(sentence_length[b * CS + p0] - 1) : 0.f;
        const float c1 = (p1 < pl) ? (float)(sentence_length[b * CS + p1] - 1) : 0.f;
        const float denom = fmaxf(c0 + c1, 1.0f);

        const fvec4* __restrict__ ss = reinterpret_cast<const fvec4*>(sent_sum);
        fvec4 a0 = ss[(size_t)(b * CS + p0) * H4 + h4];
        fvec4 a1 = ss[(size_t)(b * CS + p1) * H4 + h4];

        r = (a0 + a1) / denom;
    }

    __builtin_nontemporal_store(
        r, &reinterpret_cast<fvec4*>(cls)[(size_t)blk * H4 + h4]);
}

// ---------------------------------------------------------------------------
// Launch
// ---------------------------------------------------------------------------
extern "C" void kernel_launch(void* const* d_in, const int* in_sizes, int n_in,
                              void* d_out, int out_size, void* d_ws, size_t ws_size,
                              hipStream_t stream) {
    const int*   sentence_length = (const int*)  d_in[0];   // (B,S)
    const int*   pairs_list      = (const int*)  d_in[1];   // (B,P,2)
    const int*   passage_length  = (const int*)  d_in[2];   // (B,)
    const int*   pairs_num       = (const int*)  d_in[3];   // (B,)
    // d_in[4] = max_sentence_length scalar (compile-time CL here)
    const float* top_rep         = (const float*)d_in[5];   // (B,SEQ,H)

    float* out     = (float*)d_out;
    float* sen_emb = out;                                   // (B,S,L,H)
    float* cls     = out + (size_t)CB * CS * CL * CH;       // (B,P,1,H)

    // Workspace: partial (B*S*NCHUNK*H f32 = 15.7 MB) | sent_sum (B*S*H f32)
    float* partial  = (float*)d_ws;
    float* sent_sum = partial + (size_t)CB * CS * NCHUNK * CH;

    gather_kernel<<<CB * CS * NCHUNK, 256, 0, stream>>>(
        top_rep, sentence_length, passage_length, sen_emb, partial);

    reduce_kernel<<<CB * CS, 256, 0, stream>>>(partial, sent_sum);

    cls_kernel<<<CB * CP, 256, 0, stream>>>(
        pairs_list, pairs_num, sentence_length, passage_length, sent_sum, cls);
}

// Round 3
// 42.472 us; speedup vs baseline: 1.4043x; 1.0720x over previous
//
#include <hip/hip_runtime.h>
#include <hip/hip_bf16.h>

// Problem constants (fixed by the reference):
// B=16, S=40, P=512, L=48, SEQ=2048, H=1024
#define CB   16
#define CS   40
#define CP   512
#define CL   48
#define CSEQ 2048
#define CH   1024
#define H4   (CH / 4)        // 256 float4 per row
#define NCHUNK 4             // column groups per block (1024 threads / 256)
#define TPT  (CL / NCHUNK)   // 12 t-rows per thread

typedef float fvec4 __attribute__((ext_vector_type(4)));

// ---------------------------------------------------------------------------
// Kernel A: fused bookkeeping + sen_emb gather + in-block sent_sum reduce.
// Block = one (b,s); 1024 threads = 4 chunks x 256 float4-columns.
// Each thread gathers/stores TPT=12 t-rows and accumulates in registers;
// chunks 1..3 spill to LDS, chunk 0 finishes and stores sent_sum.
// ---------------------------------------------------------------------------
__global__ void __launch_bounds__(1024)
gather_kernel(const float* __restrict__ top_rep,
              const int* __restrict__ sentence_length,
              const int* __restrict__ passage_length,
              float* __restrict__ sen_emb,
              float* __restrict__ sent_sum) {
    const int bs    = blockIdx.x;            // b*CS + s
    const int b     = bs / CS;
    const int s     = bs - b * CS;
    const int h4    = threadIdx.x & 255;     // float4 column
    const int chunk = threadIdx.x >> 8;      // 0..3
    const int lane  = threadIdx.x & 63;

    // Redundant per-wave prefix scan over the 40 sentences of batch b.
    // tok[s'] = (s' < pl) ? sl[b,s']-1 : 0 ;  start[s] = 1 + excl_cumsum(tok)
    const int pl = passage_length[b];
    int tokl = 0;
    if (lane < CS && lane < pl) tokl = sentence_length[b * CS + lane] - 1;
    int x = tokl;
    #pragma unroll
    for (int off = 1; off < 64; off <<= 1) {
        int y = __shfl_up(x, off);
        if (lane >= off) x += y;
    }
    const int tok   = __shfl(tokl, s);
    const int start = 1 + __shfl(x, s) - tok;   // exclusive cumsum + 1

    const fvec4* __restrict__ rep =
        reinterpret_cast<const fvec4*>(top_rep) + (size_t)b * CSEQ * H4;
    fvec4* __restrict__ out =
        reinterpret_cast<fvec4*>(sen_emb) +
        ((size_t)bs * CL + (size_t)chunk * TPT) * H4;

    fvec4 acc = {0.f, 0.f, 0.f, 0.f};
    const int t0 = chunk * TPT;

    #pragma unroll 4
    for (int i = 0; i < TPT; ++i) {
        const int t = t0 + i;
        fvec4 v = {0.f, 0.f, 0.f, 0.f};
        if (t < tok) {
            // valid rows satisfy 1 <= start+t <= 1881 < SEQ; clamp for safety
            int row = start + t;
            row = min(max(row, 0), CSEQ - 1);
            v = rep[(size_t)row * H4 + h4];
        }
        __builtin_nontemporal_store(v, &out[(size_t)i * H4 + h4]);
        acc += v;
    }

    // In-block reduction of the 4 chunk partials.
    __shared__ fvec4 red[NCHUNK - 1][256];   // 12 KB
    if (chunk > 0) red[chunk - 1][h4] = acc;
    __syncthreads();
    if (chunk == 0) {
        acc += red[0][h4];
        acc += red[1][h4];
        acc += red[2][h4];
        reinterpret_cast<fvec4*>(sent_sum)[(size_t)bs * H4 + h4] = acc;
    }
}

// ---------------------------------------------------------------------------
// Kernel B: cls = masked (sent_sum[p0] + sent_sum[p1]) / max(c0+c1, 1)
// Counts derived directly from sentence_length/passage_length.
// ---------------------------------------------------------------------------
__global__ void __launch_bounds__(256)
cls_kernel(const int* __restrict__ pairs_list,
           const int* __restrict__ pairs_num,
           const int* __restrict__ sentence_length,
           const int* __restrict__ passage_length,
           const float* __restrict__ sent_sum,
           float* __restrict__ cls) {
    const int blk = blockIdx.x;              // b*CP + i
    const int b   = blk / CP;
    const int i   = blk - b * CP;
    const int h4  = threadIdx.x;

    fvec4 r = {0.f, 0.f, 0.f, 0.f};

    if (i < pairs_num[b]) {
        int p0 = pairs_list[(size_t)blk * 2 + 0];
        int p1 = pairs_list[(size_t)blk * 2 + 1];
        p0 = min(max(p0, 0), CS - 1);
        p1 = min(max(p1, 0), CS - 1);

        const int pl = passage_length[b];
        const float c0 = (p0 < pl) ? (float)(sentence_length[b * CS + p0] - 1) : 0.f;
        const float c1 = (p1 < pl) ? (float)(sentence_length[b * CS + p1] - 1) : 0.f;
        const float denom = fmaxf(c0 + c1, 1.0f);

        const fvec4* __restrict__ ss = reinterpret_cast<const fvec4*>(sent_sum);
        fvec4 a0 = ss[(size_t)(b * CS + p0) * H4 + h4];
        fvec4 a1 = ss[(size_t)(b * CS + p1) * H4 + h4];

        r = (a0 + a1) / denom;
    }

    __builtin_nontemporal_store(
        r, &reinterpret_cast<fvec4*>(cls)[(size_t)blk * H4 + h4]);
}

// ---------------------------------------------------------------------------
// Launch
// ---------------------------------------------------------------------------
extern "C" void kernel_launch(void* const* d_in, const int* in_sizes, int n_in,
                              void* d_out, int out_size, void* d_ws, size_t ws_size,
                              hipStream_t stream) {
    const int*   sentence_length = (const int*)  d_in[0];   // (B,S)
    const int*   pairs_list      = (const int*)  d_in[1];   // (B,P,2)
    const int*   passage_length  = (const int*)  d_in[2];   // (B,)
    const int*   pairs_num       = (const int*)  d_in[3];   // (B,)
    // d_in[4] = max_sentence_length scalar (compile-time CL here)
    const float* top_rep         = (const float*)d_in[5];   // (B,SEQ,H)

    float* out     = (float*)d_out;
    float* sen_emb = out;                                   // (B,S,L,H)
    float* cls     = out + (size_t)CB * CS * CL * CH;       // (B,P,1,H)

    // Workspace: sent_sum (B*S*H f32 = 2.6 MB)
    float* sent_sum = (float*)d_ws;

    gather_kernel<<<CB * CS, 1024, 0, stream>>>(
        top_rep, sentence_length, passage_length, sen_emb, sent_sum);

    cls_kernel<<<CB * CP, 256, 0, stream>>>(
        pairs_list, pairs_num, sentence_length, passage_length, sent_sum, cls);
}

// Round 4
// 42.235 us; speedup vs baseline: 1.4122x; 1.0056x over previous
//
#include <hip/hip_runtime.h>
#include <hip/hip_bf16.h>

// Problem constants (fixed by the reference):
// B=16, S=40, P=512, L=48, SEQ=2048, H=1024
#define CB   16
#define CS   40
#define CP   512
#define CL   48
#define CSEQ 2048
#define CH   1024
#define H4   (CH / 4)        // 256 float4 per row

typedef float fvec4 __attribute__((ext_vector_type(4)));

// ---------------------------------------------------------------------------
// Kernel A: fused bookkeeping + sen_emb gather + per-column sent_sum.
// Block = one (b,s); 256 threads; thread owns one float4 column and loops
// all 48 t-rows, accumulating its column sum in a register. No LDS, no
// cross-thread reduction (H-split instead of t-split). All 640 blocks
// co-resident (4 waves/block, well under the 32-wave/CU cap) -> no
// dispatch-quantization tail.
// ---------------------------------------------------------------------------
__global__ void __launch_bounds__(256)
gather_kernel(const float* __restrict__ top_rep,
              const int* __restrict__ sentence_length,
              const int* __restrict__ passage_length,
              float* __restrict__ sen_emb,
              float* __restrict__ sent_sum) {
    const int bs   = blockIdx.x;             // b*CS + s
    const int b    = bs / CS;
    const int s    = bs - b * CS;
    const int h4   = threadIdx.x;            // float4 column 0..255
    const int lane = threadIdx.x & 63;

    // Redundant per-wave prefix scan over the 40 sentences of batch b.
    // tok[s'] = (s' < pl) ? sl[b,s']-1 : 0 ;  start[s] = 1 + excl_cumsum(tok)
    const int pl = passage_length[b];
    int tokl = 0;
    if (lane < CS && lane < pl) tokl = sentence_length[b * CS + lane] - 1;
    int x = tokl;
    #pragma unroll
    for (int off = 1; off < 64; off <<= 1) {
        int y = __shfl_up(x, off);
        if (lane >= off) x += y;
    }
    const int tok   = __shfl(tokl, s);
    const int start = 1 + __shfl(x, s) - tok;   // exclusive cumsum + 1

    const fvec4* __restrict__ rep =
        reinterpret_cast<const fvec4*>(top_rep) + (size_t)b * CSEQ * H4;
    fvec4* __restrict__ out =
        reinterpret_cast<fvec4*>(sen_emb) + (size_t)bs * CL * H4;

    fvec4 acc = {0.f, 0.f, 0.f, 0.f};

    #pragma unroll 4
    for (int t = 0; t < CL; ++t) {
        fvec4 v = {0.f, 0.f, 0.f, 0.f};
        if (t < tok) {
            // valid rows satisfy 1 <= start+t <= 1880 < SEQ; clamp for safety
            int row = start + t;
            row = min(max(row, 0), CSEQ - 1);
            v = rep[(size_t)row * H4 + h4];
        }
        __builtin_nontemporal_store(v, &out[(size_t)t * H4 + h4]);
        acc += v;
    }

    reinterpret_cast<fvec4*>(sent_sum)[(size_t)bs * H4 + h4] = acc;
}

// ---------------------------------------------------------------------------
// Kernel B: cls = masked (sent_sum[p0] + sent_sum[p1]) / max(c0+c1, 1)
// Counts derived directly from sentence_length/passage_length.
// ---------------------------------------------------------------------------
__global__ void __launch_bounds__(256)
cls_kernel(const int* __restrict__ pairs_list,
           const int* __restrict__ pairs_num,
           const int* __restrict__ sentence_length,
           const int* __restrict__ passage_length,
           const float* __restrict__ sent_sum,
           float* __restrict__ cls) {
    const int blk = blockIdx.x;              // b*CP + i
    const int b   = blk / CP;
    const int i   = blk - b * CP;
    const int h4  = threadIdx.x;

    fvec4 r = {0.f, 0.f, 0.f, 0.f};

    if (i < pairs_num[b]) {
        int p0 = pairs_list[(size_t)blk * 2 + 0];
        int p1 = pairs_list[(size_t)blk * 2 + 1];
        p0 = min(max(p0, 0), CS - 1);
        p1 = min(max(p1, 0), CS - 1);

        const int pl = passage_length[b];
        const float c0 = (p0 < pl) ? (float)(sentence_length[b * CS + p0] - 1) : 0.f;
        const float c1 = (p1 < pl) ? (float)(sentence_length[b * CS + p1] - 1) : 0.f;
        const float denom = fmaxf(c0 + c1, 1.0f);

        const fvec4* __restrict__ ss = reinterpret_cast<const fvec4*>(sent_sum);
        fvec4 a0 = ss[(size_t)(b * CS + p0) * H4 + h4];
        fvec4 a1 = ss[(size_t)(b * CS + p1) * H4 + h4];

        r = (a0 + a1) / denom;
    }

    __builtin_nontemporal_store(
        r, &reinterpret_cast<fvec4*>(cls)[(size_t)blk * H4 + h4]);
}

// ---------------------------------------------------------------------------
// Launch
// ---------------------------------------------------------------------------
extern "C" void kernel_launch(void* const* d_in, const int* in_sizes, int n_in,
                              void* d_out, int out_size, void* d_ws, size_t ws_size,
                              hipStream_t stream) {
    const int*   sentence_length = (const int*)  d_in[0];   // (B,S)
    const int*   pairs_list      = (const int*)  d_in[1];   // (B,P,2)
    const int*   passage_length  = (const int*)  d_in[2];   // (B,)
    const int*   pairs_num       = (const int*)  d_in[3];   // (B,)
    // d_in[4] = max_sentence_length scalar (compile-time CL here)
    const float* top_rep         = (const float*)d_in[5];   // (B,SEQ,H)

    float* out     = (float*)d_out;
    float* sen_emb = out;                                   // (B,S,L,H)
    float* cls     = out + (size_t)CB * CS * CL * CH;       // (B,P,1,H)

    // Workspace: sent_sum (B*S*H f32 = 2.6 MB)
    float* sent_sum = (float*)d_ws;

    gather_kernel<<<CB * CS, 256, 0, stream>>>(
        top_rep, sentence_length, passage_length, sen_emb, sent_sum);

    cls_kernel<<<CB * CP, 256, 0, stream>>>(
        pairs_list, pairs_num, sentence_length, passage_length, sent_sum, cls);
}